// Round 4
// baseline (108.170 us; speedup 1.0000x reference)
//
#include <hip/hip_runtime.h>

// Problem constants (from reference)
#define UPDATE_SIZE 4096
#define BATCH 256
#define NUM_UPDATES 8
#define NUM_CH 2
#define KEEP (NUM_UPDATES * UPDATE_SIZE)               // 32768
#define SNAP ((BATCH + NUM_UPDATES - 1) * UPDATE_SIZE) // 1077248
#define OUT_LEN (BATCH * UPDATE_SIZE)                  // 1048576 = 2^20

// float4-unit constants
#define OUT4 (OUT_LEN / 4)            // 262144 = 2^18
#define SNAP4 (SNAP / 4)              // 269312
#define REST4 ((SNAP - OUT_LEN) / 4)  // 7168
#define ROW4 (KEEP / 4)               // 8192 float4 per (b,c) update row
#define UPD4 (UPDATE_SIZE / 4)        // 1024
#define TOTAL4 (2 * OUT4 + 2 * SNAP4) // 1062912 = 4152 * 256

// 4 independent coalesced streams per thread (64 B stored / thread)
#define KPT 4
#define NTHREADS (TOTAL4 / KPT)       // 265728 = 1038 * 256

typedef float f32x4 __attribute__((ext_vector_type(4)));

__device__ __forceinline__ f32x4 compute_elem(int idx,
                                              const f32x4* __restrict__ up4,
                                              const f32x4* __restrict__ sn4) {
  int c, s4;
  if (idx < 2 * OUT4) {
    c = idx >> 18;             // / OUT4
    s4 = idx & (OUT4 - 1);
  } else {
    const int r = idx - 2 * OUT4;
    c = (r >= SNAP4) ? 1 : 0;
    const int t4 = r - c * SNAP4;
    if (t4 >= REST4) {
      return (f32x4){0.f, 0.f, 0.f, 0.f};     // zero-pad of new_snapshot
    }
    s4 = OUT4 + t4;
  }

  const int q = s4 >> 10;      // window index, uniform over the 4 packed floats
  if (q >= 7 && q < BATCH) {
    // interior: exactly 8 covering windows.
    // Phase 1: issue all 9 loads (nontemporal — stream-once data, skip cache
    // allocate). Phase 2: accumulate. Keeps the whole batch in flight.
    f32x4 sn = __builtin_nontemporal_load(&sn4[c * SNAP4 + s4]);
    f32x4 u[8];
    const int base0 = (((q - 7) * NUM_CH + c) * ROW4) + (s4 - (q - 7) * UPD4);
    #pragma unroll
    for (int k = 0; k < 8; ++k) {
      // stride between consecutive b at fixed s4: 2*ROW4 - UPD4 = 15360 float4
      u[k] = __builtin_nontemporal_load(&up4[base0 + k * (NUM_CH * ROW4 - UPD4)]);
    }
    f32x4 acc = sn;
    #pragma unroll
    for (int k = 0; k < 8; ++k) acc += 0.125f * u[k];
    return acc;
  } else {
    f32x4 acc = __builtin_nontemporal_load(&sn4[c * SNAP4 + s4]);
    const int blo = (q >= 7) ? (q - 7) : 0;
    const int bhi = (q < BATCH) ? q : (BATCH - 1);
    for (int b = blo; b <= bhi; ++b) {
      acc += 0.125f * up4[(b * NUM_CH + c) * ROW4 + (s4 - b * UPD4)];
    }
    return acc;
  }
}

__global__ __launch_bounds__(256) void OnlineAverager_62680752718461_kernel(
    const float* __restrict__ update,
    const float* __restrict__ snapshot,
    float* __restrict__ out) {
  const int tid = blockIdx.x * blockDim.x + threadIdx.x;

  const f32x4* __restrict__ up4 = reinterpret_cast<const f32x4*>(update);
  const f32x4* __restrict__ sn4 = reinterpret_cast<const f32x4*>(snapshot);
  f32x4* __restrict__ o4 = reinterpret_cast<f32x4*>(out);

  // 4 independent, fully-coalesced streams: idx = tid + k*NTHREADS.
  #pragma unroll
  for (int k = 0; k < KPT; ++k) {
    const int idx = tid + k * NTHREADS;
    const f32x4 acc = compute_elem(idx, up4, sn4);
    __builtin_nontemporal_store(acc, &o4[idx]);  // stream-once output
  }
}

extern "C" void kernel_launch(void* const* d_in, const int* in_sizes, int n_in,
                              void* d_out, int out_size, void* d_ws, size_t ws_size,
                              hipStream_t stream) {
  const float* update = (const float*)d_in[0];   // (256, 2, 32768) f32
  const float* snapshot = (const float*)d_in[1]; // (2, 1077248) f32
  float* out = (float*)d_out;                    // (1,2,2^20) ++ (2,SNAP) f32

  const int threads = 256;
  const int blocks = NTHREADS / threads;         // 1038
  OnlineAverager_62680752718461_kernel<<<blocks, threads, 0, stream>>>(
      update, snapshot, out);
}

// Round 5
// 104.702 us; speedup vs baseline: 1.0331x; 1.0331x over previous
//
#include <hip/hip_runtime.h>

// Problem constants (from reference)
#define UPDATE_SIZE 4096
#define BATCH 256
#define NUM_UPDATES 8
#define NUM_CH 2
#define KEEP (NUM_UPDATES * UPDATE_SIZE)               // 32768
#define SNAP ((BATCH + NUM_UPDATES - 1) * UPDATE_SIZE) // 1077248 = 263*4096
#define OUT_LEN (BATCH * UPDATE_SIZE)                  // 1048576 = 2^20

// float4-unit constants
#define OUT4 (OUT_LEN / 4)            // 262144 = 2^18 = 256*1024
#define SNAP4 (SNAP / 4)              // 269312 = 263*1024
#define REST4 ((SNAP - OUT_LEN) / 4)  // 7168 = 7*1024
#define ROW4 (KEEP / 4)               // 8192 float4 per (b,c) update row
#define UPD4 (UPDATE_SIZE / 4)        // 1024
#define NQ 263                        // SNAP4 / UPD4

// Grid: 526 slab blocks (q,c) + 512 zero-pad blocks = 1038 blocks x 256
#define SLAB_BLOCKS (NQ * NUM_CH)     // 526
#define PAD_BLOCKS (2 * 256)          // 512

typedef float f32x4 __attribute__((ext_vector_type(4)));

__global__ __launch_bounds__(256) void OnlineAverager_62680752718461_kernel(
    const float* __restrict__ update,
    const float* __restrict__ snapshot,
    float* __restrict__ out) {
  const f32x4* __restrict__ up4 = reinterpret_cast<const f32x4*>(update);
  const f32x4* __restrict__ sn4 = reinterpret_cast<const f32x4*>(snapshot);
  f32x4* __restrict__ o4 = reinterpret_cast<f32x4*>(out);

  const int bid = blockIdx.x;
  const int t = threadIdx.x;

  if (bid < SLAB_BLOCKS) {
    // One (q,c) slab: 1024 contiguous float4 of acc.
    // Reads: 1 contiguous 16-KiB snapshot segment + nb contiguous 16-KiB
    // update segments. Writes: 1 contiguous 16-KiB output segment.
    const int q = bid >> 1;          // 0..262
    const int c = bid & 1;
    const int sbase = q * UPD4;      // slab start in float4 units
    const int obase = (q < BATCH)
        ? (c * OUT4 + sbase)                              // output tensor
        : (2 * OUT4 + c * SNAP4 + (sbase - OUT4));        // new_snapshot rest
    const int snb = c * SNAP4 + sbase;

    if (q >= 7 && q < BATCH) {
      // interior: exactly 8 covering windows, fully unrolled
      const int ub = ((q - 7) * NUM_CH + c) * ROW4 + 7 * UPD4;  // b = q-7 chunk
      #pragma unroll
      for (int i = 0; i < 4; ++i) {
        const int j = t + i * 256;
        f32x4 acc = sn4[snb + j];
        #pragma unroll
        for (int k = 0; k < 8; ++k) {
          // b = q-7+k ; chunk (q-b) = 7-k ; stride between k: 2*ROW4 - UPD4
          acc += 0.125f * up4[ub + k * (NUM_CH * ROW4 - UPD4) + j];
        }
        __builtin_nontemporal_store(acc, &o4[obase + j]);
      }
    } else {
      const int blo = (q >= 7) ? (q - 7) : 0;
      const int bhi = (q < BATCH) ? q : (BATCH - 1);
      #pragma unroll
      for (int i = 0; i < 4; ++i) {
        const int j = t + i * 256;
        f32x4 acc = sn4[snb + j];
        for (int b = blo; b <= bhi; ++b) {
          acc += 0.125f * up4[(b * NUM_CH + c) * ROW4 + (q - b) * UPD4 + j];
        }
        __builtin_nontemporal_store(acc, &o4[obase + j]);
      }
    }
  } else {
    // zero-pad of new_snapshot: pure contiguous 16-KiB fill per block
    const int r = bid - SLAB_BLOCKS; // 0..511
    const int c = r >> 8;
    const int qp = r & 255;
    const int obase = 2 * OUT4 + c * SNAP4 + REST4 + qp * UPD4;
    const f32x4 z = {0.f, 0.f, 0.f, 0.f};
    #pragma unroll
    for (int i = 0; i < 4; ++i) {
      __builtin_nontemporal_store(z, &o4[obase + t + i * 256]);
    }
  }
}

extern "C" void kernel_launch(void* const* d_in, const int* in_sizes, int n_in,
                              void* d_out, int out_size, void* d_ws, size_t ws_size,
                              hipStream_t stream) {
  const float* update = (const float*)d_in[0];   // (256, 2, 32768) f32
  const float* snapshot = (const float*)d_in[1]; // (2, 1077248) f32
  float* out = (float*)d_out;                    // (1,2,2^20) ++ (2,SNAP) f32

  const int threads = 256;
  const int blocks = SLAB_BLOCKS + PAD_BLOCKS;   // 1038
  OnlineAverager_62680752718461_kernel<<<blocks, threads, 0, stream>>>(
      update, snapshot, out);
}